// Round 1
// baseline (67.423 us; speedup 1.0000x reference)
//
#include <hip/hip_runtime.h>

#define MARGIN 0.2f
#define EPSF   1e-16f

constexpr int BSZ = 512;   // batch
constexpr int DIM = 1024;  // embedding dim

// ---------------- Kernel A: pairwise[a][n] = dot(img[a], sen[n]) ----------------
// C = A * B^T, A,B row-major [512][1024]. 16x16 tile per block.
__global__ void pairwise_gemm(const float* __restrict__ A,
                              const float* __restrict__ Bm,
                              float* __restrict__ C) {
    __shared__ float As[16][17];
    __shared__ float Bs[16][17];
    const int tx = threadIdx.x, ty = threadIdx.y;
    const int row = blockIdx.y * 16 + ty;   // a
    const int col = blockIdx.x * 16 + tx;   // n
    float acc = 0.f;
    for (int k0 = 0; k0 < DIM; k0 += 16) {
        As[ty][tx] = A[row * DIM + k0 + tx];
        Bs[ty][tx] = Bm[(blockIdx.x * 16 + ty) * DIM + k0 + tx];
        __syncthreads();
#pragma unroll
        for (int k = 0; k < 16; ++k)
            acc += As[ty][k] * Bs[tx][k];
        __syncthreads();
    }
    C[row * BSZ + col] = acc;
}

// ---------------- Kernel B: masked triplet reduction ----------------
// One block (256 threads) per anchor a.
__global__ void triplet_reduce(const float* __restrict__ pw,
                               const int*   __restrict__ labels,
                               float* __restrict__ accum) {
    __shared__ float pwrow[BSZ];
    __shared__ int   lab[BSZ];
    __shared__ int   poslist[BSZ];
    __shared__ int   npos_sh;
    __shared__ float wsum[4];
    __shared__ int   wcnt[4];

    const int a   = blockIdx.x;
    const int tid = threadIdx.x;

    if (tid == 0) npos_sh = 0;
    for (int i = tid; i < BSZ; i += 256) {
        lab[i]   = labels[i];
        pwrow[i] = pw[a * BSZ + i];
    }
    __syncthreads();

    const int la = lab[a];
    for (int p = tid; p < BSZ; p += 256) {
        if (lab[p] == la) {
            int idx = atomicAdd(&npos_sh, 1);
            poslist[idx] = p;
        }
    }
    __syncthreads();
    const int npos = npos_sh;

    float sum = 0.f;
    int   cnt = 0;
    for (int n = tid; n < BSZ; n += 256) {
        if (lab[n] != la) {
            const float pn = pwrow[n];
            for (int i = 0; i < npos; ++i) {
                float v = pwrow[poslist[i]] - pn + MARGIN;
                sum += fmaxf(v, 0.f);
                cnt += (v > EPSF) ? 1 : 0;
            }
        }
    }

    // wave (64-lane) reduce, then cross-wave via LDS
#pragma unroll
    for (int off = 32; off > 0; off >>= 1) {
        sum += __shfl_down(sum, off);
        cnt += __shfl_down(cnt, off);
    }
    const int wid = tid >> 6, lane = tid & 63;
    if (lane == 0) { wsum[wid] = sum; wcnt[wid] = cnt; }
    __syncthreads();
    if (tid == 0) {
        float s = wsum[0] + wsum[1] + wsum[2] + wsum[3];
        float c = (float)(wcnt[0] + wcnt[1] + wcnt[2] + wcnt[3]);
        atomicAdd(&accum[0], s);
        atomicAdd(&accum[1], c);
    }
}

// ---------------- Kernel C: finalize ----------------
__global__ void finalize(const float* __restrict__ accum, float* __restrict__ out) {
    out[0] = accum[0] / (accum[1] + EPSF);
}

extern "C" void kernel_launch(void* const* d_in, const int* in_sizes, int n_in,
                              void* d_out, int out_size, void* d_ws, size_t ws_size,
                              hipStream_t stream) {
    const int*   labels = (const int*)d_in[0];
    const float* img    = (const float*)d_in[1];
    const float* sen    = (const float*)d_in[2];
    float* out   = (float*)d_out;
    float* accum = (float*)d_ws;                       // [0]=sum, [1]=cnt
    float* pw    = (float*)((char*)d_ws + 256);        // 512*512*4 = 1 MB

    hipMemsetAsync(d_ws, 0, 8, stream);

    dim3 gb(16, 16);
    dim3 gg(BSZ / 16, BSZ / 16);
    pairwise_gemm<<<gg, gb, 0, stream>>>(img, sen, pw);
    triplet_reduce<<<BSZ, 256, 0, stream>>>(pw, labels, accum);
    finalize<<<1, 1, 0, stream>>>(accum, out);
}

// Round 2
// 39.337 us; speedup vs baseline: 1.7140x; 1.7140x over previous
//
#include <hip/hip_runtime.h>
#include <hip/hip_bf16.h>

#define MARGIN 0.2f
#define EPSF   1e-16f

constexpr int BSZ = 512;   // batch
constexpr int DIM = 1024;  // embedding dim

typedef __attribute__((ext_vector_type(8))) short          bf16x8;
typedef __attribute__((ext_vector_type(8))) unsigned short ushort8;
typedef __attribute__((ext_vector_type(4))) float          f32x4;

// RNE f32 -> bf16 (bit trick, matches __float2bfloat16 for finite inputs)
__device__ __forceinline__ unsigned short f2bf(float x) {
    unsigned u = __builtin_bit_cast(unsigned, x);
    unsigned r = u + 0x7FFFu + ((u >> 16) & 1u);
    return (unsigned short)(r >> 16);
}

// ---------------- Kernel 0: f32 -> bf16 convert (img and sen) ----------------
// 8 floats per thread. Threads [0, N8) -> img, [N8, 2*N8) -> sen.
__global__ void __launch_bounds__(256) cvt_bf16(const float* __restrict__ img,
                                                const float* __restrict__ sen,
                                                unsigned short* __restrict__ ib,
                                                unsigned short* __restrict__ sb) {
    const int N8 = BSZ * DIM / 8;   // 65536
    int i = blockIdx.x * 256 + threadIdx.x;
    const float* src;
    unsigned short* dst;
    int j;
    if (i < N8) { src = img; dst = ib; j = i; }
    else        { src = sen; dst = sb; j = i - N8; }
    float4 v0 = ((const float4*)src)[j * 2];
    float4 v1 = ((const float4*)src)[j * 2 + 1];
    ushort8 o;
    o[0] = f2bf(v0.x); o[1] = f2bf(v0.y); o[2] = f2bf(v0.z); o[3] = f2bf(v0.w);
    o[4] = f2bf(v1.x); o[5] = f2bf(v1.y); o[6] = f2bf(v1.z); o[7] = f2bf(v1.w);
    ((ushort8*)dst)[j] = o;
}

// ---------------- Kernel A: MFMA GEMM, pairwise[a][n] = dot(img[a], sen[n]) ----
// One 16x16 C tile per wave; 4 waves/block; 256 blocks = 1024 tiles (32x32).
// mfma_f32_16x16x32_bf16 fragment layout (verified m89/m91):
//   A: row = lane&15, k = (lane>>4)*8 + j  (8 contiguous k per lane)
//   B: col = lane&15, k = (lane>>4)*8 + j  (B[k][n] = S[n][k] -> contiguous in S row)
//   C/D: col = lane&15, row = (lane>>4)*4 + reg
__global__ void __launch_bounds__(256) mfma_gemm(const unsigned short* __restrict__ I,
                                                 const unsigned short* __restrict__ S,
                                                 float* __restrict__ C) {
    const int lane = threadIdx.x & 63;
    const int wid  = threadIdx.x >> 6;
    const int tile = blockIdx.x * 4 + wid;       // 0..1023
    const int tr   = (tile >> 5) * 16;           // a base
    const int tc   = (tile & 31) * 16;           // n base
    const int r    = lane & 15;
    const int kb   = (lane >> 4) * 8;

    const bf16x8* Ap = (const bf16x8*)(I + (tr + r) * DIM + kb);
    const bf16x8* Bp = (const bf16x8*)(S + (tc + r) * DIM + kb);

    f32x4 acc0 = {0.f, 0.f, 0.f, 0.f};
    f32x4 acc1 = {0.f, 0.f, 0.f, 0.f};
#pragma unroll
    for (int t = 0; t < DIM / 32; t += 2) {      // 32 k-steps, 2 chains
        acc0 = __builtin_amdgcn_mfma_f32_16x16x32_bf16(Ap[t * 4],     Bp[t * 4],     acc0, 0, 0, 0);
        acc1 = __builtin_amdgcn_mfma_f32_16x16x32_bf16(Ap[t * 4 + 4], Bp[t * 4 + 4], acc1, 0, 0, 0);
    }
    acc0 += acc1;

    const int orow = tr + (lane >> 4) * 4;
    const int ocol = tc + r;
#pragma unroll
    for (int q = 0; q < 4; ++q)
        C[(orow + q) * BSZ + ocol] = acc0[q];
}

// ---------------- Kernel B: masked triplet reduction ----------------
__global__ void triplet_reduce(const float* __restrict__ pw,
                               const int*   __restrict__ labels,
                               float* __restrict__ accum) {
    __shared__ float pwrow[BSZ];
    __shared__ int   lab[BSZ];
    __shared__ int   poslist[BSZ];
    __shared__ int   npos_sh;
    __shared__ float wsum[4];
    __shared__ int   wcnt[4];

    const int a   = blockIdx.x;
    const int tid = threadIdx.x;

    if (tid == 0) npos_sh = 0;
    for (int i = tid; i < BSZ; i += 256) {
        lab[i]   = labels[i];
        pwrow[i] = pw[a * BSZ + i];
    }
    __syncthreads();

    const int la = lab[a];
    for (int p = tid; p < BSZ; p += 256) {
        if (lab[p] == la) {
            int idx = atomicAdd(&npos_sh, 1);
            poslist[idx] = p;
        }
    }
    __syncthreads();
    const int npos = npos_sh;

    float sum = 0.f;
    int   cnt = 0;
    for (int n = tid; n < BSZ; n += 256) {
        if (lab[n] != la) {
            const float pn = pwrow[n];
            for (int i = 0; i < npos; ++i) {
                float v = pwrow[poslist[i]] - pn + MARGIN;
                sum += fmaxf(v, 0.f);
                cnt += (v > EPSF) ? 1 : 0;
            }
        }
    }

#pragma unroll
    for (int off = 32; off > 0; off >>= 1) {
        sum += __shfl_down(sum, off);
        cnt += __shfl_down(cnt, off);
    }
    const int wid = tid >> 6, lane = tid & 63;
    if (lane == 0) { wsum[wid] = sum; wcnt[wid] = cnt; }
    __syncthreads();
    if (tid == 0) {
        float s = wsum[0] + wsum[1] + wsum[2] + wsum[3];
        float c = (float)(wcnt[0] + wcnt[1] + wcnt[2] + wcnt[3]);
        atomicAdd(&accum[0], s);
        atomicAdd(&accum[1], c);
    }
}

// ---------------- Kernel C: finalize ----------------
__global__ void finalize(const float* __restrict__ accum, float* __restrict__ out) {
    out[0] = accum[0] / (accum[1] + EPSF);
}

extern "C" void kernel_launch(void* const* d_in, const int* in_sizes, int n_in,
                              void* d_out, int out_size, void* d_ws, size_t ws_size,
                              hipStream_t stream) {
    const int*   labels = (const int*)d_in[0];
    const float* img    = (const float*)d_in[1];
    const float* sen    = (const float*)d_in[2];
    float* out = (float*)d_out;

    // workspace layout
    float*          accum = (float*)d_ws;                               // 8 B (+pad)
    float*          pw    = (float*)((char*)d_ws + 256);                // 1 MB
    unsigned short* ib    = (unsigned short*)((char*)d_ws + 256 + (1u << 20));            // 1 MB
    unsigned short* sb    = (unsigned short*)((char*)d_ws + 256 + (1u << 20) * 2);        // 1 MB

    hipMemsetAsync(d_ws, 0, 8, stream);

    cvt_bf16<<<512, 256, 0, stream>>>(img, sen, ib, sb);                // 2*65536 threads
    mfma_gemm<<<256, 256, 0, stream>>>(ib, sb, pw);
    triplet_reduce<<<BSZ, 256, 0, stream>>>(pw, labels, accum);
    finalize<<<1, 1, 0, stream>>>(accum, out);
}

// Round 3
// 26.866 us; speedup vs baseline: 2.5096x; 1.4642x over previous
//
#include <hip/hip_runtime.h>

#define MARGIN 0.2f
#define EPSF   1e-16f

constexpr int BSZ = 512;   // batch
constexpr int DIM = 1024;  // embedding dim

typedef __attribute__((ext_vector_type(8))) short    bf16x8;
typedef __attribute__((ext_vector_type(4))) unsigned uint4v;
typedef __attribute__((ext_vector_type(4))) float    f32x4;

// 8x f32 -> 8x bf16 via v_cvt_pk_bf16_f32 (RNE). Order within the lane's
// 8-element k-chunk is irrelevant as long as A and B use the same packing
// (dot product is k-permutation invariant).
__device__ __forceinline__ bf16x8 cvt8(float4 a, float4 b) {
    uint4v u;
    asm("v_cvt_pk_bf16_f32 %0, %1, %2" : "=v"(u[0]) : "v"(a.x), "v"(a.y));
    asm("v_cvt_pk_bf16_f32 %0, %1, %2" : "=v"(u[1]) : "v"(a.z), "v"(a.w));
    asm("v_cvt_pk_bf16_f32 %0, %1, %2" : "=v"(u[2]) : "v"(b.x), "v"(b.y));
    asm("v_cvt_pk_bf16_f32 %0, %1, %2" : "=v"(u[3]) : "v"(b.z), "v"(b.w));
    return __builtin_bit_cast(bf16x8, u);
}

// ---------------- Kernel A: MFMA GEMM with in-register f32->bf16 ----------------
// pairwise[a][n] = dot(img[a], sen[n]). One 16x16 C tile per wave;
// 4 waves/block; 256 blocks = 1024 tiles (32x32 tile grid).
// mfma_f32_16x16x32_bf16 layout: A/B: row|col = lane&15, k = (lane>>4)*8 + j;
// C/D: col = lane&15, row = (lane>>4)*4 + reg.
__global__ void __launch_bounds__(256) mfma_gemm(const float* __restrict__ I,
                                                 const float* __restrict__ S,
                                                 float* __restrict__ C) {
    const int lane = threadIdx.x & 63;
    const int wid  = threadIdx.x >> 6;
    const int tile = blockIdx.x * 4 + wid;       // 0..1023
    const int tr   = (tile >> 5) * 16;           // a base
    const int tc   = (tile & 31) * 16;           // n base
    const int r    = lane & 15;
    const int kb   = (lane >> 4) * 8;            // k offset (floats)

    const float4* Af = (const float4*)(I + (size_t)(tr + r) * DIM + kb);
    const float4* Bf = (const float4*)(S + (size_t)(tc + r) * DIM + kb);

    f32x4 acc0 = {0.f, 0.f, 0.f, 0.f};
    f32x4 acc1 = {0.f, 0.f, 0.f, 0.f};
#pragma unroll
    for (int t = 0; t < DIM / 32; t += 2) {      // 32 k-steps, 2 acc chains
        acc0 = __builtin_amdgcn_mfma_f32_16x16x32_bf16(
                   cvt8(Af[t * 8],     Af[t * 8 + 1]),
                   cvt8(Bf[t * 8],     Bf[t * 8 + 1]), acc0, 0, 0, 0);
        acc1 = __builtin_amdgcn_mfma_f32_16x16x32_bf16(
                   cvt8(Af[t * 8 + 8], Af[t * 8 + 9]),
                   cvt8(Bf[t * 8 + 8], Bf[t * 8 + 9]), acc1, 0, 0, 0);
    }
    acc0 += acc1;

    const int orow = tr + (lane >> 4) * 4;
    const int ocol = tc + r;
#pragma unroll
    for (int q = 0; q < 4; ++q)
        C[(orow + q) * BSZ + ocol] = acc0[q];
}

// ---------------- Kernel B: masked triplet reduction -> per-block partials ----
// One block (256 threads) per anchor a. Writes psum[a], pcnt[a] (no init needed).
__global__ void triplet_reduce(const float* __restrict__ pw,
                               const int*   __restrict__ labels,
                               float* __restrict__ psum,
                               float* __restrict__ pcnt) {
    __shared__ float pwrow[BSZ];
    __shared__ int   lab[BSZ];
    __shared__ int   poslist[BSZ];
    __shared__ int   npos_sh;
    __shared__ float wsum[4];
    __shared__ int   wcnt[4];

    const int a   = blockIdx.x;
    const int tid = threadIdx.x;

    if (tid == 0) npos_sh = 0;
    for (int i = tid; i < BSZ; i += 256) {
        lab[i]   = labels[i];
        pwrow[i] = pw[a * BSZ + i];
    }
    __syncthreads();

    const int la = lab[a];
    for (int p = tid; p < BSZ; p += 256) {
        if (lab[p] == la) {
            int idx = atomicAdd(&npos_sh, 1);
            poslist[idx] = p;
        }
    }
    __syncthreads();
    const int npos = npos_sh;

    float sum = 0.f;
    int   cnt = 0;
    for (int n = tid; n < BSZ; n += 256) {
        if (lab[n] != la) {
            const float pn = pwrow[n];
            for (int i = 0; i < npos; ++i) {
                float v = pwrow[poslist[i]] - pn + MARGIN;
                sum += fmaxf(v, 0.f);
                cnt += (v > EPSF) ? 1 : 0;
            }
        }
    }

#pragma unroll
    for (int off = 32; off > 0; off >>= 1) {
        sum += __shfl_down(sum, off);
        cnt += __shfl_down(cnt, off);
    }
    const int wid = tid >> 6, lane = tid & 63;
    if (lane == 0) { wsum[wid] = sum; wcnt[wid] = cnt; }
    __syncthreads();
    if (tid == 0) {
        psum[a] = wsum[0] + wsum[1] + wsum[2] + wsum[3];
        pcnt[a] = (float)(wcnt[0] + wcnt[1] + wcnt[2] + wcnt[3]);
    }
}

// ---------------- Kernel C: finalize over 512 partials ----------------
__global__ void __launch_bounds__(512) finalize(const float* __restrict__ psum,
                                                const float* __restrict__ pcnt,
                                                float* __restrict__ out) {
    __shared__ float wsum[8], wcnt[8];
    const int tid = threadIdx.x;
    float s = psum[tid];
    float c = pcnt[tid];
#pragma unroll
    for (int off = 32; off > 0; off >>= 1) {
        s += __shfl_down(s, off);
        c += __shfl_down(c, off);
    }
    const int wid = tid >> 6, lane = tid & 63;
    if (lane == 0) { wsum[wid] = s; wcnt[wid] = c; }
    __syncthreads();
    if (tid == 0) {
        float S = 0.f, C = 0.f;
#pragma unroll
        for (int i = 0; i < 8; ++i) { S += wsum[i]; C += wcnt[i]; }
        out[0] = S / (C + EPSF);
    }
}

extern "C" void kernel_launch(void* const* d_in, const int* in_sizes, int n_in,
                              void* d_out, int out_size, void* d_ws, size_t ws_size,
                              hipStream_t stream) {
    const int*   labels = (const int*)d_in[0];
    const float* img    = (const float*)d_in[1];
    const float* sen    = (const float*)d_in[2];
    float* out = (float*)d_out;

    // workspace layout (all fully written every call -> no init needed)
    float* pw   = (float*)d_ws;                                  // 1 MB
    float* psum = (float*)((char*)d_ws + (1u << 20));            // 2 KB
    float* pcnt = (float*)((char*)d_ws + (1u << 20) + 2048);     // 2 KB

    mfma_gemm<<<256, 256, 0, stream>>>(img, sen, pw);
    triplet_reduce<<<BSZ, 256, 0, stream>>>(pw, labels, psum, pcnt);
    finalize<<<1, 512, 0, stream>>>(psum, pcnt, out);
}